// Round 9
// baseline (144.764 us; speedup 1.0000x reference)
//
#include <hip/hip_runtime.h>
#include <hip/hip_bf16.h>

typedef unsigned short u16;
typedef __attribute__((ext_vector_type(8))) short bf16x8;
typedef __attribute__((ext_vector_type(4))) float f32x4;
typedef __attribute__((ext_vector_type(4))) int i32x4;
typedef __attribute__((ext_vector_type(2))) unsigned int u32x2;

constexpr int SEN  = 128;
constexpr int CIN  = 270;
constexpr int KA   = 352;          // A row: 336 real K + 16 zero pad
constexpr int NOUT = 984;
constexpr int XROW = 256;          // bytes per xT row (16 slots x 16B)
constexpr int XTB  = 130 * XROW;   // 33,280 B per buffer

__device__ inline float ftanh(float x) {
    float e = __expf(2.0f * x);
    return 1.0f - 2.0f * __builtin_amdgcn_rcpf(e + 1.0f);
}
__device__ inline unsigned pk2(float x, float y) {
    union { __hip_bfloat162 h; unsigned u; } v;
    v.h = __float22bfloat162_rn(float2{x, y});
    return v.u;
}

// ---------------------------------------------------------------------------
// prep_all: Av[128][352] bf16 (K = tap*112 + ch, ch<110 real), SE3, SR3, loc.
// blocks [0,176): Av  [176,236): SE3  [236,716): SR3  [716,2764): loc
// ---------------------------------------------------------------------------
__global__ void prep_all(const float* __restrict__ w, const float* __restrict__ ee,
                         const float* __restrict__ re, const int* __restrict__ loc,
                         const int* __restrict__ lmark, const float* __restrict__ we,
                         u16* __restrict__ Av, float* __restrict__ SE3,
                         float* __restrict__ SR3, float* __restrict__ out) {
    const int b = blockIdx.x, tid = threadIdx.x;
    if (b < 176) {
        int i = b * 256 + tid;                // < 45056
        int dc = i / KA, K = i - dc * KA;
        int tap = (K >= 112) + (K >= 224) + (K >= 336);
        int ch  = K - 112 * tap;
        float v = (tap < 3 && ch < 110) ? w[(dc * CIN + ch) * 3 + tap] : 0.0f;
        union { __hip_bfloat16 h; u16 u; } cv;
        cv.h = __float2bfloat16(v);
        Av[i] = cv.u;
    } else if (b < 236) {
        int i = (b - 176) * 256 + tid;        // < 15360
        int k = i % 3, rest = i / 3;
        int dc = rest & 127, e = rest >> 7;
        float a = 0.f;
        for (int j = 0; j < 32; ++j)
            a += w[(dc * CIN + 110 + j) * 3 + k] * ee[e * 32 + j];
        SE3[i] = a;
    } else if (b < 716) {
        int i = (b - 236) * 256 + tid;        // < 122880
        int k = i % 3, rest = i / 3;
        int dc = rest & 127, rr = rest >> 7;
        int r = rr % 40, j = rr / 40;
        float a = 0.f;
        for (int d = 0; d < 16; ++d)
            a += w[(dc * CIN + 142 + j * 16 + d) * 3 + k] * re[r * 16 + d];
        SR3[i] = a;
    } else {
        int li = b - 716;                     // 0..2047, two samples per block
        int s = li * 2 + (tid >> 7);
        int d = tid & 127;
        if (d < 100) {
            const int* L = loc + (size_t)s * 16;
            float* o = out + (size_t)s * NOUT + 384;
#pragma unroll
            for (int i = 0; i < 4; ++i)
                o[i * 100 + d] = ftanh(we[(size_t)L[i] * 100 + d]);
            int mk = lmark[s];
            float acc = 0.f;
            for (int j = 0; j < mk; ++j)
                acc += we[(size_t)L[4 + j] * 100 + d];
            o[4 * 100 + d] = ftanh(acc / (float)mk);
            o[5 * 100 + d] = ftanh(we[(size_t)L[4 + mk] * 100 + d]);
        }
    }
}

// ---------------------------------------------------------------------------
// Main: 512 blocks x 512 thr (8 waves), 2 blocks/CU. Wave w computes
// dc [w*16, w*16+16) over 128 tokens (16x16x32, K=336 via 11 chunks).
// A streams from L2 inside the K-loop (NO register residency, NO spill);
// pointer laundered per sample so the compiler can't CSE across samples.
// All waves stage the next sample (double-buffered LDS), 1 barrier/sample.
// ---------------------------------------------------------------------------
__global__ __launch_bounds__(512)
__attribute__((amdgpu_waves_per_eu(4)))
void conv_pool(const int* __restrict__ inp, const int* __restrict__ pos1,
               const int* __restrict__ pos2, const int* __restrict__ subtype,
               const int* __restrict__ argRole,
               const float* __restrict__ maskL, const float* __restrict__ maskM,
               const float* __restrict__ maskR,
               const float* __restrict__ we, const float* __restrict__ pe,
               const float* __restrict__ cb,
               const u16* __restrict__ Av, const float* __restrict__ SE3,
               const float* __restrict__ SR3, float* __restrict__ out)
{
    __shared__ __align__(16) char xT[2][XTB];   // 66,560 B
    __shared__ float sc[2][3 * 128];            //  3,072 B
    __shared__ float msk[2][3 * 128];           //  3,072 B

    const int tid  = threadIdx.x;
    const int lane = tid & 63;
    const int wid  = tid >> 6;        // wave: dc slice [wid*16, wid*16+16)
    const int cl   = lane & 15;
    const int rg   = lane >> 4;

    // zero both xT buffers once (pad rows 0/129 and slots 14,15 stay zero)
    {
        i32x4 z = {0, 0, 0, 0};
        i32x4* pz = (i32x4*)xT;
#pragma unroll
        for (int i = 0; i < 9; ++i) {
            int o = tid + i * 512;
            if (o < 2 * XTB / 16) pz[o] = z;
        }
    }
    __syncthreads();   // zero-fill must complete before any staging writes

    // per-lane A base (loads stay IN the K-loop, stream from L2)
    const char* apBase = (const char*)Av + (wid * 16 + cl) * (KA * 2) + rg * 16;

    // ---- B byte-offsets per chunk (sample-invariant, 11 VGPRs) ----
    // tap clamped to 2: K >= 336 lanes read slots 14/15 (always zero), and
    // row0 stays <= cl+2 so nf=7 reads row <= 129 (in bounds).
    int addrB[11];
#pragma unroll
    for (int c = 0; c < 11; ++c) {
        int g   = 32 * c + 8 * rg;
        int tap = (g >= 112) + (g >= 224);
        int ch  = g - 112 * tap;
        int row0 = cl + tap;
        int phys = (ch >> 3) ^ (row0 & 15);
        addrB[c] = row0 * XROW + (phys << 4);
    }

    const int sbase = blockIdx.x * 8;

    auto stage = [&](int s, char* xb, float* scb, float* mb) {
        // coalesced word-embedding gather: flat float4 index q over [0,3200)
#pragma unroll
        for (int jj = 0; jj < 7; ++jj) {
            int q = tid + jj * 512;
            if (q < 3200) {
                int tok = q / 25;
                int e   = q - tok * 25;
                int idx = inp[s * SEN + tok];
                f32x4 v = *(const f32x4*)(we + (size_t)idx * 100 + e * 4);
                int row  = tok + 1;
                int phys = (e >> 1) ^ (row & 15);
                u32x2 wv = { pk2(v[0], v[1]), pk2(v[2], v[3]) };
                *(u32x2*)(xb + row * XROW + (phys << 4) + (e & 1) * 8) = wv;
            }
        }
        if (tid < 128) {
            // const-channel sums for dc = tid
            int sub = subtype[s];
            i32x4 a0 = *(const i32x4*)(argRole + s * 8);
            i32x4 a1 = *(const i32x4*)(argRole + s * 8 + 4);
            int arr[8] = {a0[0], a0[1], a0[2], a0[3], a1[0], a1[1], a1[2], a1[3]};
            const float* bb = SE3 + (sub * 128 + tid) * 3;
            float sk0 = bb[0], sk1 = bb[1], sk2 = bb[2];
#pragma unroll
            for (int j = 0; j < 8; ++j) {
                const float* rb = SR3 + ((j * 40 + arr[j]) * 128 + tid) * 3;
                sk0 += rb[0]; sk1 += rb[1]; sk2 += rb[2];
            }
            scb[tid]       = sk0 + sk1 + sk2 + cb[tid];
            scb[128 + tid] = sk0;
            scb[256 + tid] = sk2;
        } else if (tid < 256) {
            // position embeddings for token t
            int t = tid - 128;
            int row = t + 1, rx = row & 15;
            int p1 = pos1[s * SEN + t];
            int p2 = pos2[s * SEN + t];
            float q0 = pe[p1 * 5],     q1 = pe[p1 * 5 + 1], q2 = pe[p1 * 5 + 2];
            float q3 = pe[p1 * 5 + 3], q4 = pe[p1 * 5 + 4];
            float r0 = pe[p2 * 5],     r1 = pe[p2 * 5 + 1], r2 = pe[p2 * 5 + 2];
            float r3 = pe[p2 * 5 + 3], r4 = pe[p2 * 5 + 4];
            u32x2 wa = { pk2(q0, q1), pk2(q2, q3) };          // ch 100..103
            *(u32x2*)(xb + row * XROW + ((12 ^ rx) << 4) + 8) = wa;
            union { bf16x8 v; unsigned u[4]; } wb;             // ch 104..111
            wb.u[0] = pk2(q4, r0); wb.u[1] = pk2(r1, r2);
            wb.u[2] = pk2(r3, r4); wb.u[3] = 0;
            *(bf16x8*)(xb + row * XROW + ((13 ^ rx) << 4)) = wb.v;
        } else if (tid < 352) {
            // masks -> LDS, f4-coalesced
            int i = tid - 256;                 // < 96
            int m = i >> 5, j4 = i & 31;
            const float* msrc = (m == 0) ? maskL : (m == 1) ? maskM : maskR;
            *(f32x4*)(mb + m * 128 + j4 * 4) =
                *(const f32x4*)(msrc + (size_t)s * SEN + j4 * 4);
        }
    };

    // prologue: stage sample 0 into buffer 0
    stage(sbase, xT[0], sc[0], msk[0]);
    __syncthreads();

    for (int it = 0; it < 8; ++it) {
        const int s   = sbase + it;
        const int cur = it & 1;
        const char* xc = xT[cur];

        // launder A pointer: forbid CSE of A-loads across samples (keeps
        // per-sample register footprint small; loads pipeline inside K-loop)
        const char* ap = apBase;
        asm volatile("" : "+v"(ap));

        // ---- GEMM: 11 chunks x 8 token-blocks, A streamed from L2 ----
        f32x4 acc[8];
#pragma unroll
        for (int nf = 0; nf < 8; ++nf) acc[nf] = (f32x4){0.f, 0.f, 0.f, 0.f};

#pragma unroll
        for (int c = 0; c < 11; ++c) {
            const bf16x8 a = *(const bf16x8*)(ap + c * 64);
#pragma unroll
            for (int nf = 0; nf < 8; ++nf) {
                bf16x8 b = *(const bf16x8*)(xc + addrB[c] + nf * 4096);
                acc[nf] = __builtin_amdgcn_mfma_f32_16x16x32_bf16(
                    a, b, acc[nf], 0, 0, 0);
            }
        }

        // ---- epilogue: masked max-pool in registers ----
        const float* scc = sc[cur];
        const float* mc  = msk[cur];
        float sall[4], s0v[4], s2v[4];
#pragma unroll
        for (int r = 0; r < 4; ++r) {
            int dc = wid * 16 + rg * 4 + r;
            sall[r] = scc[dc]; s0v[r] = scc[128 + dc]; s2v[r] = scc[256 + dc];
        }
        float pm[3][4];
#pragma unroll
        for (int m = 0; m < 3; ++m)
#pragma unroll
            for (int r = 0; r < 4; ++r) pm[m][r] = -1e30f;

#pragma unroll
        for (int nf = 0; nf < 8; ++nf) {
            const int tt = nf * 16 + cl;
            const float m0 = mc[tt], m1 = mc[128 + tt], m2 = mc[256 + tt];
#pragma unroll
            for (int r = 0; r < 4; ++r) {
                float v = acc[nf][r] + sall[r];
                if (nf == 0) v -= (cl == 0)  ? s0v[r] : 0.f;   // token 0
                if (nf == 7) v -= (cl == 15) ? s2v[r] : 0.f;   // token 127
                pm[0][r] = fmaxf(pm[0][r], __builtin_fmaf(v, m0, 1.f));
                pm[1][r] = fmaxf(pm[1][r], __builtin_fmaf(v, m1, 1.f));
                pm[2][r] = fmaxf(pm[2][r], __builtin_fmaf(v, m2, 1.f));
            }
        }
#pragma unroll
        for (int m = 0; m < 3; ++m)
#pragma unroll
            for (int r = 0; r < 4; ++r)
#pragma unroll
                for (int d = 1; d < 16; d <<= 1)
                    pm[m][r] = fmaxf(pm[m][r], __shfl_xor(pm[m][r], d));
        if (cl < 3) {
            float* o = out + (size_t)s * NOUT + cl * 128 + wid * 16 + rg * 4;
#pragma unroll
            for (int r = 0; r < 4; ++r) {
                float v = (cl == 0) ? pm[0][r] : (cl == 1) ? pm[1][r] : pm[2][r];
                o[r] = ftanh(v - 1.f);
            }
        }

        // ---- stage next sample into the other buffer ----
        if (it < 7) stage(s + 1, xT[cur ^ 1], sc[cur ^ 1], msk[cur ^ 1]);
        __syncthreads();
    }
}

// ---------------------------------------------------------------------------
extern "C" void kernel_launch(void* const* d_in, const int* in_sizes, int n_in,
                              void* d_out, int out_size, void* d_ws, size_t ws_size,
                              hipStream_t stream) {
    const int*   inp     = (const int*)d_in[0];
    const int*   pos1    = (const int*)d_in[1];
    const int*   pos2    = (const int*)d_in[2];
    const int*   loc     = (const int*)d_in[3];
    const int*   lmark   = (const int*)d_in[4];
    const int*   subtype = (const int*)d_in[5];
    const int*   argRole = (const int*)d_in[6];
    const float* maskL   = (const float*)d_in[7];
    const float* maskM   = (const float*)d_in[8];
    const float* maskR   = (const float*)d_in[9];
    const float* we      = (const float*)d_in[10];
    const float* pe      = (const float*)d_in[11];
    const float* ee      = (const float*)d_in[12];
    const float* re      = (const float*)d_in[13];
    const float* cw      = (const float*)d_in[14];
    const float* cb      = (const float*)d_in[15];
    float* out = (float*)d_out;

    char* ws = (char*)d_ws;
    u16*   Av  = (u16*)ws;                         // 128*352*2 = 90,112 B
    float* SE3 = (float*)(ws + 90112);             // 61,440 B
    float* SR3 = (float*)(ws + 90112 + 61440);     // 491,520 B

    hipLaunchKernelGGL(prep_all, dim3(2764), dim3(256), 0, stream,
                       cw, ee, re, loc, lmark, we, Av, SE3, SR3, out);
    hipLaunchKernelGGL(conv_pool, dim3(512), dim3(512), 0, stream,
                       inp, pos1, pos2, subtype, argRole, maskL, maskM, maskR,
                       we, pe, cb, Av, SE3, SR3, out);
}

// Round 10
// 97.798 us; speedup vs baseline: 1.4802x; 1.4802x over previous
//
#include <hip/hip_runtime.h>
#include <hip/hip_bf16.h>

typedef unsigned short u16;
typedef __attribute__((ext_vector_type(8))) short bf16x8;
typedef __attribute__((ext_vector_type(4))) float f32x4;
typedef __attribute__((ext_vector_type(4))) int i32x4;
typedef __attribute__((ext_vector_type(2))) unsigned int u32x2;

constexpr int SEN  = 128;
constexpr int CIN  = 270;
constexpr int KA   = 352;          // A row: 336 real K + 16 zero pad
constexpr int NOUT = 984;
constexpr int XROW = 256;          // bytes per xT row (16 slots x 16B)
constexpr int XTB  = 130 * XROW;   // 33,280 B per buffer
constexpr int WEBP = 256;          // bf16 word-table row pitch (bytes)
constexpr size_t WS_BASE = 90112 + 61440 + 491520;          // Av+SE3+SR3
constexpr size_t WS_NEED = WS_BASE + 50000ull * WEBP;       // +12.8 MB

__device__ inline float ftanh(float x) {
    float e = __expf(2.0f * x);
    return 1.0f - 2.0f * __builtin_amdgcn_rcpf(e + 1.0f);
}
__device__ inline unsigned pk2(float x, float y) {
    union { __hip_bfloat162 h; unsigned u; } v;
    v.h = __float22bfloat162_rn(float2{x, y});
    return v.u;
}
__device__ __forceinline__ void gload_lds16(const void* g, void* l) {
    __builtin_amdgcn_global_load_lds(
        (const __attribute__((address_space(1))) void*)g,
        (__attribute__((address_space(3))) void*)l, 16, 0, 0);
}

// ---------------------------------------------------------------------------
// prep_all: Av[128][352] bf16, SE3, SR3, loc path, and (GLD mode) the bf16
// word table weB[50000][128] (row pitch 256B, cols 100..127 = 0).
// blocks [0,176): Av  [176,236): SE3  [236,716): SR3  [716,2764): loc
//        [2764, 15264): weB (launched only when ws fits)
// ---------------------------------------------------------------------------
__global__ void prep_all(const float* __restrict__ w, const float* __restrict__ ee,
                         const float* __restrict__ re, const int* __restrict__ loc,
                         const int* __restrict__ lmark, const float* __restrict__ we,
                         u16* __restrict__ Av, float* __restrict__ SE3,
                         float* __restrict__ SR3, u16* __restrict__ weB,
                         float* __restrict__ out) {
    const int b = blockIdx.x, tid = threadIdx.x;
    if (b < 176) {
        int i = b * 256 + tid;                // < 45056
        int dc = i / KA, K = i - dc * KA;
        int tap = (K >= 112) + (K >= 224) + (K >= 336);
        int ch  = K - 112 * tap;
        float v = (tap < 3 && ch < 110) ? w[(dc * CIN + ch) * 3 + tap] : 0.0f;
        union { __hip_bfloat16 h; u16 u; } cv;
        cv.h = __float2bfloat16(v);
        Av[i] = cv.u;
    } else if (b < 236) {
        int i = (b - 176) * 256 + tid;        // < 15360
        int k = i % 3, rest = i / 3;
        int dc = rest & 127, e = rest >> 7;
        float a = 0.f;
        for (int j = 0; j < 32; ++j)
            a += w[(dc * CIN + 110 + j) * 3 + k] * ee[e * 32 + j];
        SE3[i] = a;
    } else if (b < 716) {
        int i = (b - 236) * 256 + tid;        // < 122880
        int k = i % 3, rest = i / 3;
        int dc = rest & 127, rr = rest >> 7;
        int r = rr % 40, j = rr / 40;
        float a = 0.f;
        for (int d = 0; d < 16; ++d)
            a += w[(dc * CIN + 142 + j * 16 + d) * 3 + k] * re[r * 16 + d];
        SR3[i] = a;
    } else if (b < 2764) {
        int li = b - 716;                     // 0..2047, two samples per block
        int s = li * 2 + (tid >> 7);
        int d = tid & 127;
        if (d < 100) {
            const int* L = loc + (size_t)s * 16;
            float* o = out + (size_t)s * NOUT + 384;
#pragma unroll
            for (int i = 0; i < 4; ++i)
                o[i * 100 + d] = ftanh(we[(size_t)L[i] * 100 + d]);
            int mk = lmark[s];
            float acc = 0.f;
            for (int j = 0; j < mk; ++j)
                acc += we[(size_t)L[4 + j] * 100 + d];
            o[4 * 100 + d] = ftanh(acc / (float)mk);
            o[5 * 100 + d] = ftanh(we[(size_t)L[4 + mk] * 100 + d]);
        }
    } else {
        // bf16 word table: i over u32 pairs, 50000*64 entries
        size_t i = (size_t)(b - 2764) * 256 + tid;   // < 3,200,000
        int v  = (int)(i >> 6), cp = (int)(i & 63);
        int c0 = cp * 2;
        float x0 = (c0     < 100) ? we[(size_t)v * 100 + c0]     : 0.f;
        float x1 = (c0 + 1 < 100) ? we[(size_t)v * 100 + c0 + 1] : 0.f;
        ((unsigned*)weB)[(size_t)v * 64 + cp] = pk2(x0, x1);
    }
}

// ---------------------------------------------------------------------------
// Main: 512 blocks x 512 thr (8 waves), 2 blocks/CU. Wave w computes
// dc [w*16,w*16+16) x 128 tokens (16x16x32, K=336 via 11 chunks, A from L2).
// GLD=true: word+mask staging via async global_load_lds issued one sample
// ahead (latency hidden under GEMM); pe/sc loads issued early into regs,
// committed after the barrier. GLD=false: R9-style reg-roundtrip staging.
// ---------------------------------------------------------------------------
template <bool GLD>
__global__ __launch_bounds__(512)
__attribute__((amdgpu_waves_per_eu(4)))
void conv_pool(const int* __restrict__ inp, const int* __restrict__ pos1,
               const int* __restrict__ pos2, const int* __restrict__ subtype,
               const int* __restrict__ argRole,
               const float* __restrict__ maskL, const float* __restrict__ maskM,
               const float* __restrict__ maskR,
               const float* __restrict__ we, const float* __restrict__ pe,
               const float* __restrict__ cb,
               const u16* __restrict__ Av, const float* __restrict__ SE3,
               const float* __restrict__ SR3, const u16* __restrict__ weB,
               float* __restrict__ out)
{
    __shared__ __align__(16) char xT[2][XTB];   // 66,560 B
    __shared__ float sc[2][3 * 128];            //  3,072 B
    __shared__ float msk[2][3 * 128];           //  3,072 B

    const int tid  = threadIdx.x;
    const int lane = tid & 63;
    const int wid  = tid >> 6;        // wave: dc slice [wid*16, wid*16+16)
    const int cl   = lane & 15;
    const int rg   = lane >> 4;

    // zero both xT buffers once (rows 0/129 and pad slots stay zero)
    {
        i32x4 z = {0, 0, 0, 0};
        i32x4* pz = (i32x4*)xT;
#pragma unroll
        for (int i = 0; i < 9; ++i) {
            int o = tid + i * 512;
            if (o < 2 * XTB / 16) pz[o] = z;
        }
    }
    __syncthreads();

    const char* apBase = (const char*)Av + (wid * 16 + cl) * (KA * 2) + rg * 16;

    // B byte-offsets per chunk (tap clamped to 2; K>=336 hits A-zero region)
    int addrB[11];
#pragma unroll
    for (int c = 0; c < 11; ++c) {
        int g   = 32 * c + 8 * rg;
        int tap = (g >= 112) + (g >= 224);
        int ch  = g - 112 * tap;
        int row0 = cl + tap;
        int phys = (ch >> 3) ^ (row0 & 15);
        addrB[c] = row0 * XROW + (phys << 4);
    }

    const int sbase = blockIdx.x * 8;

    // ---- persistent small-stage registers ----
    float sk0 = 0.f, sk1 = 0.f, sk2 = 0.f;
    float cbv = (tid < 128) ? cb[tid] : 0.f;
    float pp[10];
#pragma unroll
    for (int i = 0; i < 10; ++i) pp[i] = 0.f;

    // async word+mask gather for sample s into buffer xb / mask row mb
    auto issueGather = [&](int s, char* xb, float* mb) {
#pragma unroll
        for (int q = 0; q < 4; ++q) {
            const int j   = (wid << 2) + q;            // 0..31
            const int tok = (j << 2) + (lane >> 4);    // 4 tokens per instr
            const int idx = inp[s * SEN + tok];
            const int e   = (lane & 15) ^ ((tok + 1) & 15);  // pre-swizzled src
            const char* src = (const char*)weB + (size_t)idx * WEBP + (e << 4);
            gload_lds16(src, xb + XROW + (j << 10));
        }
        if (wid == 4) {   // masks: L+M in one instr, R in a half instr
            const char* gL = (const char*)(maskL + (size_t)s * SEN);
            const char* gM = (const char*)(maskM + (size_t)s * SEN);
            const char* gR = (const char*)(maskR + (size_t)s * SEN);
            const char* s1 = (lane < 32) ? gL + (lane << 4)
                                         : gM + ((lane - 32) << 4);
            gload_lds16(s1, (char*)mb);
            if (lane < 32)
                gload_lds16(gR + (lane << 4), (char*)mb + 1024);
        }
    };

    // issue small loads (sc sums, pe) for sample s into registers
    auto smallLoad = [&](int s) {
        if (tid < 128) {
            int sub = subtype[s];
            i32x4 a0 = *(const i32x4*)(argRole + s * 8);
            i32x4 a1 = *(const i32x4*)(argRole + s * 8 + 4);
            int arr[8] = {a0[0], a0[1], a0[2], a0[3], a1[0], a1[1], a1[2], a1[3]};
            const float* bb = SE3 + (sub * 128 + tid) * 3;
            sk0 = bb[0]; sk1 = bb[1]; sk2 = bb[2];
#pragma unroll
            for (int j = 0; j < 8; ++j) {
                const float* rb = SR3 + ((j * 40 + arr[j]) * 128 + tid) * 3;
                sk0 += rb[0]; sk1 += rb[1]; sk2 += rb[2];
            }
        } else if (tid < 256) {
            int t = tid - 128;
            int p1 = pos1[s * SEN + t], p2 = pos2[s * SEN + t];
#pragma unroll
            for (int i = 0; i < 5; ++i) {
                pp[i]     = pe[p1 * 5 + i];
                pp[5 + i] = pe[p2 * 5 + i];
            }
        }
    };

    // commit small state into LDS (after gld_lds drained by the barrier)
    auto smallCommit = [&](int s, char* xb, float* scb, float* mb) {
        if (tid < 128) {
            scb[tid]       = sk0 + sk1 + sk2 + cbv;
            scb[128 + tid] = sk0;
            scb[256 + tid] = sk2;
        } else if (tid < 256) {
            int t = tid - 128, row = t + 1, rx = row & 15;
            u32x2 wa = { pk2(pp[0], pp[1]), pk2(pp[2], pp[3]) };   // ch 100..103
            *(u32x2*)(xb + row * XROW + ((12 ^ rx) << 4) + 8) = wa;
            union { bf16x8 v; unsigned u[4]; } wb;                  // ch 104..111
            wb.u[0] = pk2(pp[4], pp[5]); wb.u[1] = pk2(pp[6], pp[7]);
            wb.u[2] = pk2(pp[8], pp[9]); wb.u[3] = 0;
            *(bf16x8*)(xb + row * XROW + ((13 ^ rx) << 4)) = wb.v;
        }
        if constexpr (!GLD) {
            // fallback: reg-roundtrip word gather + mask copy (R9 style)
#pragma unroll
            for (int jj = 0; jj < 7; ++jj) {
                int q = tid + jj * 512;
                if (q < 3200) {
                    int tok = q / 25;
                    int e   = q - tok * 25;
                    int idx = inp[s * SEN + tok];
                    f32x4 v = *(const f32x4*)(we + (size_t)idx * 100 + e * 4);
                    int row  = tok + 1;
                    int phys = (e >> 1) ^ (row & 15);
                    u32x2 wv = { pk2(v[0], v[1]), pk2(v[2], v[3]) };
                    *(u32x2*)(xb + row * XROW + (phys << 4) + (e & 1) * 8) = wv;
                }
            }
            if (tid >= 256 && tid < 352) {
                int i = tid - 256;
                int m = i >> 5, j4 = i & 31;
                const float* msrc = (m == 0) ? maskL : (m == 1) ? maskM : maskR;
                *(f32x4*)(mb + m * 128 + j4 * 4) =
                    *(const f32x4*)(msrc + (size_t)s * SEN + j4 * 4);
            }
        }
    };

    // ---- prologue: stage sample sbase into buffer 0 ----
    smallLoad(sbase);
    if constexpr (GLD) issueGather(sbase, xT[0], msk[0]);
    __syncthreads();                       // drains gather into buf 0
    smallCommit(sbase, xT[0], sc[0], msk[0]);
    __syncthreads();

    for (int it = 0; it < 8; ++it) {
        const int s   = sbase + it;
        const int cur = it & 1;
        const char* xc = xT[cur];

        if (it < 7) {
            if constexpr (GLD) issueGather(s + 1, xT[cur ^ 1], msk[cur ^ 1]);
            smallLoad(s + 1);
        }

        // launder A pointer (forbid cross-sample CSE / register blow-up)
        const char* ap = apBase;
        asm volatile("" : "+v"(ap));

        // ---- GEMM: 11 chunks x 8 token-blocks, A streamed from L2 ----
        f32x4 acc[8];
#pragma unroll
        for (int nf = 0; nf < 8; ++nf) acc[nf] = (f32x4){0.f, 0.f, 0.f, 0.f};

#pragma unroll
        for (int c = 0; c < 11; ++c) {
            const bf16x8 a = *(const bf16x8*)(ap + c * 64);
#pragma unroll
            for (int nf = 0; nf < 8; ++nf) {
                bf16x8 b = *(const bf16x8*)(xc + addrB[c] + nf * 4096);
                acc[nf] = __builtin_amdgcn_mfma_f32_16x16x32_bf16(
                    a, b, acc[nf], 0, 0, 0);
            }
        }

        // ---- epilogue: masked max-pool in registers ----
        const float* scc = sc[cur];
        const float* mc  = msk[cur];
        float sall[4], s0v[4], s2v[4];
#pragma unroll
        for (int r = 0; r < 4; ++r) {
            int dc = wid * 16 + rg * 4 + r;
            sall[r] = scc[dc]; s0v[r] = scc[128 + dc]; s2v[r] = scc[256 + dc];
        }
        float pm[3][4];
#pragma unroll
        for (int m = 0; m < 3; ++m)
#pragma unroll
            for (int r = 0; r < 4; ++r) pm[m][r] = -1e30f;

#pragma unroll
        for (int nf = 0; nf < 8; ++nf) {
            const int tt = nf * 16 + cl;
            const float m0 = mc[tt], m1 = mc[128 + tt], m2 = mc[256 + tt];
#pragma unroll
            for (int r = 0; r < 4; ++r) {
                float v = acc[nf][r] + sall[r];
                if (nf == 0) v -= (cl == 0)  ? s0v[r] : 0.f;   // token 0
                if (nf == 7) v -= (cl == 15) ? s2v[r] : 0.f;   // token 127
                pm[0][r] = fmaxf(pm[0][r], __builtin_fmaf(v, m0, 1.f));
                pm[1][r] = fmaxf(pm[1][r], __builtin_fmaf(v, m1, 1.f));
                pm[2][r] = fmaxf(pm[2][r], __builtin_fmaf(v, m2, 1.f));
            }
        }
#pragma unroll
        for (int m = 0; m < 3; ++m)
#pragma unroll
            for (int r = 0; r < 4; ++r)
#pragma unroll
                for (int d = 1; d < 16; d <<= 1)
                    pm[m][r] = fmaxf(pm[m][r], __shfl_xor(pm[m][r], d));
        if (cl < 3) {
            float* o = out + (size_t)s * NOUT + cl * 128 + wid * 16 + rg * 4;
#pragma unroll
            for (int r = 0; r < 4; ++r) {
                float v = (cl == 0) ? pm[0][r] : (cl == 1) ? pm[1][r] : pm[2][r];
                o[r] = ftanh(v - 1.f);
            }
        }

        __syncthreads();   // drains gather(s+1) writes; all reads of cur done
        if (it < 7) smallCommit(s + 1, xT[cur ^ 1], sc[cur ^ 1], msk[cur ^ 1]);
        __syncthreads();
    }
}

// ---------------------------------------------------------------------------
extern "C" void kernel_launch(void* const* d_in, const int* in_sizes, int n_in,
                              void* d_out, int out_size, void* d_ws, size_t ws_size,
                              hipStream_t stream) {
    const int*   inp     = (const int*)d_in[0];
    const int*   pos1    = (const int*)d_in[1];
    const int*   pos2    = (const int*)d_in[2];
    const int*   loc     = (const int*)d_in[3];
    const int*   lmark   = (const int*)d_in[4];
    const int*   subtype = (const int*)d_in[5];
    const int*   argRole = (const int*)d_in[6];
    const float* maskL   = (const float*)d_in[7];
    const float* maskM   = (const float*)d_in[8];
    const float* maskR   = (const float*)d_in[9];
    const float* we      = (const float*)d_in[10];
    const float* pe      = (const float*)d_in[11];
    const float* ee      = (const float*)d_in[12];
    const float* re      = (const float*)d_in[13];
    const float* cw      = (const float*)d_in[14];
    const float* cb      = (const float*)d_in[15];
    float* out = (float*)d_out;

    char* ws = (char*)d_ws;
    u16*   Av  = (u16*)ws;                         // 90,112 B
    float* SE3 = (float*)(ws + 90112);             // 61,440 B
    float* SR3 = (float*)(ws + 90112 + 61440);     // 491,520 B
    u16*   weB = (u16*)(ws + WS_BASE);             // 12,800,000 B (GLD mode)

    const bool gld = (ws_size >= WS_NEED);
    const int prepGrid = gld ? 15264 : 2764;

    hipLaunchKernelGGL(prep_all, dim3(prepGrid), dim3(256), 0, stream,
                       cw, ee, re, loc, lmark, we, Av, SE3, SR3, weB, out);
    if (gld) {
        hipLaunchKernelGGL((conv_pool<true>), dim3(512), dim3(512), 0, stream,
                           inp, pos1, pos2, subtype, argRole, maskL, maskM, maskR,
                           we, pe, cb, Av, SE3, SR3, weB, out);
    } else {
        hipLaunchKernelGGL((conv_pool<false>), dim3(512), dim3(512), 0, stream,
                           inp, pos1, pos2, subtype, argRole, maskL, maskM, maskR,
                           we, pe, cb, Av, SE3, SR3, weB, out);
    }
}